// Round 16
// baseline (67.916 us; speedup 1.0000x reference)
//
#include <hip/hip_runtime.h>
#include <stdint.h>

#define NTOK 8192
#define NCOL 4096     // DIM == VOCAB
#define RANK 256
#define TPB  128      // tokens per block (4 waves x 32 tokens)
#define CPB  256      // cols per block (16 col-tiles)

typedef __attribute__((ext_vector_type(8))) short bf16x8;
typedef __attribute__((ext_vector_type(4))) float f32x4;

__device__ __forceinline__ unsigned short f2bf(float f) {
    unsigned int u = __float_as_uint(f);
    u += 0x7fffu + ((u >> 16) & 1u);   // RNE
    return (unsigned short)(u >> 16);
}

// async global->LDS, 16B per lane; LDS dest = uniform base + lane*16 (m104)
__device__ __forceinline__ void gload_lds16(const uint4* g, uint4* l) {
    __builtin_amdgcn_global_load_lds(
        (const __attribute__((address_space(1))) void*)g,
        (__attribute__((address_space(3))) void*)l, 16, 0, 0);
}

// ---- combined pre-pass ----
// blocks [0, 1024): A fp32 [4096][256] -> bf16 row-major (Abf, 2 MiB, L2-resident)
// blocks [1024, 1536): B fp32 [256][4096] -> bf16 MFMA-B-fragment order
//   frag layout: flat uint4 index = (ct*8 + ks)*64 + lane, 8 bf16 each:
//     element j = B[ks*32 + (lane>>4)*8 + j][ct*16 + (lane&15)]
__global__ __launch_bounds__(256) void prep_kernel(
    const float* __restrict__ A, const float* __restrict__ B,
    unsigned short* __restrict__ Abf, unsigned short* __restrict__ Bfrag)
{
    if (blockIdx.x < 1024) {
        int i = blockIdx.x * 256 + threadIdx.x;
        float4 v = reinterpret_cast<const float4*>(A)[i];
        ushort4 o;
        o.x = f2bf(v.x); o.y = f2bf(v.y); o.z = f2bf(v.z); o.w = f2bf(v.w);
        reinterpret_cast<ushort4*>(Abf)[i] = o;
    } else {
        int gt = (blockIdx.x - 1024) * 256 + threadIdx.x;
        int ct = gt >> 9;
        int rem = gt & 511;
        int ks = rem >> 6;
        int ln = rem & 63;
        int col = ct * 16 + (ln & 15);
        int kb  = ks * 32 + ((ln >> 4) << 3);
        unsigned short pk[8];
        #pragma unroll
        for (int j = 0; j < 8; ++j)
            pk[j] = f2bf(B[(size_t)(kb + j) * NCOL + col]);
        uint4 o;
        o.x = (unsigned)pk[0] | ((unsigned)pk[1] << 16);
        o.y = (unsigned)pk[2] | ((unsigned)pk[3] << 16);
        o.z = (unsigned)pk[4] | ((unsigned)pk[5] << 16);
        o.w = (unsigned)pk[6] | ((unsigned)pk[7] << 16);
        reinterpret_cast<uint4*>(Bfrag)[gt] = o;
    }
}

// ---- main: fused gather + LoRA GEMM + W add + mask ----
// r15 structure (LDS-staged B, W-ring depth 4, counted-vmcnt + raw barrier)
// + ONE change: output stores are NONTEMPORAL. 134 MB of write-once data no
// longer evicts Bfrag/Abf/warm-W lines from the 4 MiB per-XCD L2s, so the
// gather latency the ring is covering shrinks.
__global__ __launch_bounds__(256) void emb_lora_mfma(
    const int* __restrict__ x,
    const int* __restrict__ mask,
    const float* __restrict__ W,
    const unsigned short* __restrict__ Abf,
    const unsigned short* __restrict__ Bfrag,
    float* __restrict__ out)
{
    __shared__ int s_idx[TPB];
    __shared__ int s_msk[TPB];
    __shared__ uint4 b_lds[2][512];   // 2 x 8 KB (one B col-tile each)

    const int tid  = threadIdx.x;
    const int lane = tid & 63;
    const int wave = tid >> 6;        // wave owns tokens [wave*32, wave*32+32)
    const int tok0 = blockIdx.x * TPB;
    const int col0 = blockIdx.y * CPB;

    if (tid < TPB) {
        s_idx[tid] = x[tok0 + tid];
        s_msk[tid] = mask[tok0 + tid];
    }
    __syncthreads();

    // A fragments for both token groups (A-operand row = lane&15)
    const int a0row = s_idx[wave * 32 + (lane & 15)];
    const int a1row = s_idx[wave * 32 + 16 + (lane & 15)];
    const unsigned short* ap0 = Abf + (size_t)a0row * RANK + ((lane >> 4) << 3);
    const unsigned short* ap1 = Abf + (size_t)a1row * RANK + ((lane >> 4) << 3);
    bf16x8 aA[8], aB[8];
    #pragma unroll
    for (int s = 0; s < 8; ++s) {
        aA[s] = *reinterpret_cast<const bf16x8*>(ap0 + s * 32);
        aB[s] = *reinterpret_cast<const bf16x8*>(ap1 + s * 32);
    }

    // per-thread epilogue state: group g covers rows wave*32+g*16+(lane>>4)*4+r
    const int colb = col0 + (lane & 15);
    int msk0[4], msk1[4];
    unsigned woff0[4], woff1[4], ooff0[4], ooff1[4];
    #pragma unroll
    for (int r = 0; r < 4; ++r) {
        int row0 = wave * 32 + ((lane >> 4) << 2) + r;
        int row1 = row0 + 16;
        msk0[r] = s_msk[row0];
        msk1[r] = s_msk[row1];
        woff0[r] = (unsigned)s_idx[row0] * NCOL + colb;
        woff1[r] = (unsigned)s_idx[row1] * NCOL + colb;
        ooff0[r] = (unsigned)(tok0 + row0) * NCOL + colb;
        ooff1[r] = (unsigned)(tok0 + row1) * NCOL + colb;
    }

    // block's 16 col-tiles start at global col-tile blockIdx.y*16
    const uint4* bpanel = reinterpret_cast<const uint4*>(Bfrag)
                          + (size_t)(blockIdx.y * 16) * 512;

    // W prefetch rings, depth 4 (r11 win), exec-masked loads
    // (explicit `if`, NOT ternary — r3: speculation doubled FETCH_SIZE)
    float wv0[4][4], wv1[4][4];
    #pragma unroll
    for (int p = 0; p < 4; ++p) {
        #pragma unroll
        for (int r = 0; r < 4; ++r) {
            float v0 = 0.0f, v1 = 0.0f;
            if (!msk0[r]) v0 = W[woff0[r] + p * 16];
            if (!msk1[r]) v1 = W[woff1[r] + p * 16];
            wv0[p][r] = v0;
            wv1[p][r] = v1;
        }
    }

    // stage: wave stages its 2 KB of tile T into buffer BUF (async)
#define STAGE(T, BUF)                                                    \
    {                                                                    \
        const uint4* gs = bpanel + (T) * 512 + wave * 128 + lane;        \
        gload_lds16(gs,      &b_lds[BUF][wave * 128]);                   \
        gload_lds16(gs + 64, &b_lds[BUF][wave * 128 + 64]);              \
    }

    STAGE(0, 0);
    __syncthreads();   // one-time full drain: tile 0 staged, prologue done

#define TILE_BODY(T, BUF, SLOT, PF, LAST)                                \
    {                                                                    \
        const int t_ = (T);                                              \
        /* copy current W slot to regs BEFORE the slot is re-prefetched */ \
        float wc0[4], wc1[4];                                            \
        _Pragma("unroll")                                                \
        for (int r = 0; r < 4; ++r) { wc0[r] = wv0[SLOT][r]; wc1[r] = wv1[SLOT][r]; } \
        if (PF) {                                                        \
            _Pragma("unroll")                                            \
            for (int r = 0; r < 4; ++r) {                                \
                float v0 = 0.0f, v1 = 0.0f;                              \
                if (!msk0[r]) v0 = W[woff0[r] + (t_ + 4) * 16];          \
                if (!msk1[r]) v1 = W[woff1[r] + (t_ + 4) * 16];          \
                wv0[SLOT][r] = v0;                                       \
                wv1[SLOT][r] = v1;                                       \
            }                                                            \
        }                                                                \
        if (!(LAST)) { STAGE(t_ + 1, 1 - (BUF)); }                       \
        /* pin: all loads above issue before everything below */         \
        __builtin_amdgcn_sched_barrier(0);                               \
        uint4 bb[8];                                                     \
        _Pragma("unroll")                                                \
        for (int s = 0; s < 8; ++s)                                      \
            bb[s] = b_lds[BUF][s * 64 + lane];                           \
        f32x4 acc00 = {0.f,0.f,0.f,0.f}, acc01 = {0.f,0.f,0.f,0.f};      \
        f32x4 acc10 = {0.f,0.f,0.f,0.f}, acc11 = {0.f,0.f,0.f,0.f};      \
        _Pragma("unroll")                                                \
        for (int s = 0; s < 4; ++s) {                                    \
            bf16x8 b0 = __builtin_bit_cast(bf16x8, bb[s]);               \
            bf16x8 b1 = __builtin_bit_cast(bf16x8, bb[s + 4]);           \
            acc00 = __builtin_amdgcn_mfma_f32_16x16x32_bf16(aA[s],     b0, acc00, 0, 0, 0); \
            acc01 = __builtin_amdgcn_mfma_f32_16x16x32_bf16(aA[s + 4], b1, acc01, 0, 0, 0); \
            acc10 = __builtin_amdgcn_mfma_f32_16x16x32_bf16(aB[s],     b0, acc10, 0, 0, 0); \
            acc11 = __builtin_amdgcn_mfma_f32_16x16x32_bf16(aB[s + 4], b1, acc11, 0, 0, 0); \
        }                                                                \
        _Pragma("unroll")                                                \
        for (int r = 0; r < 4; ++r) {                                    \
            float v0 = msk0[r] ? 0.0f : (acc00[r] + acc01[r] + wc0[r]);  \
            float v1 = msk1[r] ? 0.0f : (acc10[r] + acc11[r] + wc1[r]);  \
            __builtin_nontemporal_store(v0, &out[ooff0[r] + t_ * 16]);   \
            __builtin_nontemporal_store(v1, &out[ooff1[r] + t_ * 16]);   \
        }                                                                \
        if (!(LAST)) {                                                   \
            /* counted wait: the 8 stores above are the ONLY ops allowed \
               outstanding -> stage loads (issued before them) are done; \
               stores never block the barrier (T4). */                   \
            asm volatile("s_waitcnt vmcnt(8)" ::: "memory");             \
            __builtin_amdgcn_s_barrier();                                \
        }                                                                \
    }

    TILE_BODY(0,  0, 0, 1, 0);
    TILE_BODY(1,  1, 1, 1, 0);
    TILE_BODY(2,  0, 2, 1, 0);
    TILE_BODY(3,  1, 3, 1, 0);
    TILE_BODY(4,  0, 0, 1, 0);
    TILE_BODY(5,  1, 1, 1, 0);
    TILE_BODY(6,  0, 2, 1, 0);
    TILE_BODY(7,  1, 3, 1, 0);
    TILE_BODY(8,  0, 0, 1, 0);
    TILE_BODY(9,  1, 1, 1, 0);
    TILE_BODY(10, 0, 2, 1, 0);
    TILE_BODY(11, 1, 3, 1, 0);
    // peeled tail: no W prefetch (avoids OOB reads past the block's col range)
    TILE_BODY(12, 0, 0, 0, 0);
    TILE_BODY(13, 1, 1, 0, 0);
    TILE_BODY(14, 0, 2, 0, 0);
    TILE_BODY(15, 1, 3, 0, 1);
#undef TILE_BODY
#undef STAGE
}

extern "C" void kernel_launch(void* const* d_in, const int* in_sizes, int n_in,
                              void* d_out, int out_size, void* d_ws, size_t ws_size,
                              hipStream_t stream) {
    (void)in_sizes; (void)n_in; (void)out_size; (void)ws_size;

    const int*   x    = (const int*)d_in[0];
    const int*   mask = (const int*)d_in[1];
    const float* W    = (const float*)d_in[2];
    const float* A    = (const float*)d_in[3];
    const float* B    = (const float*)d_in[4];
    float*       out  = (float*)d_out;

    unsigned short* Abf   = (unsigned short*)d_ws;                       // 2 MiB
    unsigned short* Bfrag = (unsigned short*)((char*)d_ws + (2u << 20)); // 2 MiB

    prep_kernel<<<dim3(1536), dim3(256), 0, stream>>>(A, B, Abf, Bfrag);

    dim3 grid(NTOK / TPB, NCOL / CPB);   // (64, 16) = 1024 blocks
    emb_lora_mfma<<<grid, dim3(256), 0, stream>>>(x, mask, W, Abf, Bfrag, out);
}

// Round 17
// 49.088 us; speedup vs baseline: 1.3836x; 1.3836x over previous
//
#include <hip/hip_runtime.h>
#include <stdint.h>

#define NTOK 8192
#define NCOL 4096     // DIM == VOCAB
#define RANK 256
#define TPB  128      // tokens per block (4 waves x 32 tokens)
#define CPB  256      // cols per block (16 col-tiles)

typedef __attribute__((ext_vector_type(8))) short bf16x8;
typedef __attribute__((ext_vector_type(4))) float f32x4;

__device__ __forceinline__ unsigned short f2bf(float f) {
    unsigned int u = __float_as_uint(f);
    u += 0x7fffu + ((u >> 16) & 1u);   // RNE
    return (unsigned short)(u >> 16);
}

// async global->LDS, 16B per lane; LDS dest = uniform base + lane*16 (m104)
__device__ __forceinline__ void gload_lds16(const uint4* g, uint4* l) {
    __builtin_amdgcn_global_load_lds(
        (const __attribute__((address_space(1))) void*)g,
        (__attribute__((address_space(3))) void*)l, 16, 0, 0);
}

// ---- combined pre-pass ----
// blocks [0, 1024): A fp32 [4096][256] -> bf16 row-major (Abf, 2 MiB, L2-resident)
// blocks [1024, 1536): B fp32 [256][4096] -> bf16 MFMA-B-fragment order
//   frag layout: flat uint4 index = (ct*8 + ks)*64 + lane, 8 bf16 each:
//     element j = B[ks*32 + (lane>>4)*8 + j][ct*16 + (lane&15)]
__global__ __launch_bounds__(256) void prep_kernel(
    const float* __restrict__ A, const float* __restrict__ B,
    unsigned short* __restrict__ Abf, unsigned short* __restrict__ Bfrag)
{
    if (blockIdx.x < 1024) {
        int i = blockIdx.x * 256 + threadIdx.x;
        float4 v = reinterpret_cast<const float4*>(A)[i];
        ushort4 o;
        o.x = f2bf(v.x); o.y = f2bf(v.y); o.z = f2bf(v.z); o.w = f2bf(v.w);
        reinterpret_cast<ushort4*>(Abf)[i] = o;
    } else {
        int gt = (blockIdx.x - 1024) * 256 + threadIdx.x;
        int ct = gt >> 9;
        int rem = gt & 511;
        int ks = rem >> 6;
        int ln = rem & 63;
        int col = ct * 16 + (ln & 15);
        int kb  = ks * 32 + ((ln >> 4) << 3);
        unsigned short pk[8];
        #pragma unroll
        for (int j = 0; j < 8; ++j)
            pk[j] = f2bf(B[(size_t)(kb + j) * NCOL + col]);
        uint4 o;
        o.x = (unsigned)pk[0] | ((unsigned)pk[1] << 16);
        o.y = (unsigned)pk[2] | ((unsigned)pk[3] << 16);
        o.z = (unsigned)pk[4] | ((unsigned)pk[5] << 16);
        o.w = (unsigned)pk[6] | ((unsigned)pk[7] << 16);
        reinterpret_cast<uint4*>(Bfrag)[gt] = o;
    }
}

// ---- main: fused gather + LoRA GEMM + W add + mask ----
// r15 base (LDS-staged B, W-ring 4, counted vmcnt + raw barrier; NO nt
// stores — r16 showed nt wrecks the warm path) + ONE change: 2 tiles per
// barrier phase with 4 staging buffers. 8 barriers instead of 16; 32 MFMAs
// of slack between barriers.
__global__ __launch_bounds__(256) void emb_lora_mfma(
    const int* __restrict__ x,
    const int* __restrict__ mask,
    const float* __restrict__ W,
    const unsigned short* __restrict__ Abf,
    const unsigned short* __restrict__ Bfrag,
    float* __restrict__ out)
{
    __shared__ int s_idx[TPB];
    __shared__ int s_msk[TPB];
    __shared__ uint4 b_lds[4][512];   // 4 x 8 KB staging buffers

    const int tid  = threadIdx.x;
    const int lane = tid & 63;
    const int wave = tid >> 6;        // wave owns tokens [wave*32, wave*32+32)
    const int tok0 = blockIdx.x * TPB;
    const int col0 = blockIdx.y * CPB;

    if (tid < TPB) {
        s_idx[tid] = x[tok0 + tid];
        s_msk[tid] = mask[tok0 + tid];
    }
    __syncthreads();

    // A fragments for both token groups (A-operand row = lane&15)
    const int a0row = s_idx[wave * 32 + (lane & 15)];
    const int a1row = s_idx[wave * 32 + 16 + (lane & 15)];
    const unsigned short* ap0 = Abf + (size_t)a0row * RANK + ((lane >> 4) << 3);
    const unsigned short* ap1 = Abf + (size_t)a1row * RANK + ((lane >> 4) << 3);
    bf16x8 aA[8], aB[8];
    #pragma unroll
    for (int s = 0; s < 8; ++s) {
        aA[s] = *reinterpret_cast<const bf16x8*>(ap0 + s * 32);
        aB[s] = *reinterpret_cast<const bf16x8*>(ap1 + s * 32);
    }

    // per-thread epilogue state: group g covers rows wave*32+g*16+(lane>>4)*4+r
    const int colb = col0 + (lane & 15);
    int msk0[4], msk1[4];
    unsigned woff0[4], woff1[4], ooff0[4], ooff1[4];
    #pragma unroll
    for (int r = 0; r < 4; ++r) {
        int row0 = wave * 32 + ((lane >> 4) << 2) + r;
        int row1 = row0 + 16;
        msk0[r] = s_msk[row0];
        msk1[r] = s_msk[row1];
        woff0[r] = (unsigned)s_idx[row0] * NCOL + colb;
        woff1[r] = (unsigned)s_idx[row1] * NCOL + colb;
        ooff0[r] = (unsigned)(tok0 + row0) * NCOL + colb;
        ooff1[r] = (unsigned)(tok0 + row1) * NCOL + colb;
    }

    // block's 16 col-tiles start at global col-tile blockIdx.y*16
    const uint4* bpanel = reinterpret_cast<const uint4*>(Bfrag)
                          + (size_t)(blockIdx.y * 16) * 512;

    // W prefetch rings, depth 4, exec-masked loads
    // (explicit `if`, NOT ternary — r3: speculation doubled FETCH_SIZE)
    float wv0[4][4], wv1[4][4];
    #pragma unroll
    for (int p = 0; p < 4; ++p) {
        #pragma unroll
        for (int r = 0; r < 4; ++r) {
            float v0 = 0.0f, v1 = 0.0f;
            if (!msk0[r]) v0 = W[woff0[r] + p * 16];
            if (!msk1[r]) v1 = W[woff1[r] + p * 16];
            wv0[p][r] = v0;
            wv1[p][r] = v1;
        }
    }

    // stage: wave stages its 2 KB of tile T into buffer BUF (async)
#define STAGE(T, BUF)                                                    \
    {                                                                    \
        const uint4* gs = bpanel + (T) * 512 + wave * 128 + lane;        \
        gload_lds16(gs,      &b_lds[BUF][wave * 128]);                   \
        gload_lds16(gs + 64, &b_lds[BUF][wave * 128 + 64]);              \
    }

    // one tile's compute+store (W values passed in regs)
#define TCOMP(T, WC0, WC1)                                               \
    {                                                                    \
        uint4 bb[8];                                                     \
        _Pragma("unroll")                                                \
        for (int s = 0; s < 8; ++s)                                      \
            bb[s] = b_lds[(T) & 3][s * 64 + lane];                       \
        f32x4 acc00 = {0.f,0.f,0.f,0.f}, acc01 = {0.f,0.f,0.f,0.f};      \
        f32x4 acc10 = {0.f,0.f,0.f,0.f}, acc11 = {0.f,0.f,0.f,0.f};      \
        _Pragma("unroll")                                                \
        for (int s = 0; s < 4; ++s) {                                    \
            bf16x8 b0 = __builtin_bit_cast(bf16x8, bb[s]);               \
            bf16x8 b1 = __builtin_bit_cast(bf16x8, bb[s + 4]);           \
            acc00 = __builtin_amdgcn_mfma_f32_16x16x32_bf16(aA[s],     b0, acc00, 0, 0, 0); \
            acc01 = __builtin_amdgcn_mfma_f32_16x16x32_bf16(aA[s + 4], b1, acc01, 0, 0, 0); \
            acc10 = __builtin_amdgcn_mfma_f32_16x16x32_bf16(aB[s],     b0, acc10, 0, 0, 0); \
            acc11 = __builtin_amdgcn_mfma_f32_16x16x32_bf16(aB[s + 4], b1, acc11, 0, 0, 0); \
        }                                                                \
        _Pragma("unroll")                                                \
        for (int r = 0; r < 4; ++r) {                                    \
            float v0 = msk0[r] ? 0.0f : (acc00[r] + acc01[r] + WC0[r]);  \
            float v1 = msk1[r] ? 0.0f : (acc10[r] + acc11[r] + WC1[r]);  \
            out[ooff0[r] + (T) * 16] = v0;                               \
            out[ooff1[r] + (T) * 16] = v1;                               \
        }                                                                \
    }

    // phase: compute tiles T,T+1; stage T+2,T+3; prefetch W T+4,T+5
#define PHASE(T, PF, LAST)                                               \
    {                                                                    \
        float wcA0[4], wcA1[4], wcB0[4], wcB1[4];                        \
        _Pragma("unroll")                                                \
        for (int r = 0; r < 4; ++r) {                                    \
            wcA0[r] = wv0[(T) & 3][r];     wcA1[r] = wv1[(T) & 3][r];    \
            wcB0[r] = wv0[(T + 1) & 3][r]; wcB1[r] = wv1[(T + 1) & 3][r];\
        }                                                                \
        if (PF) {                                                        \
            _Pragma("unroll")                                            \
            for (int r = 0; r < 4; ++r) {                                \
                float v0 = 0.0f, v1 = 0.0f;                              \
                if (!msk0[r]) v0 = W[woff0[r] + ((T) + 4) * 16];         \
                if (!msk1[r]) v1 = W[woff1[r] + ((T) + 4) * 16];         \
                wv0[(T) & 3][r] = v0;                                    \
                wv1[(T) & 3][r] = v1;                                    \
                float u0 = 0.0f, u1 = 0.0f;                              \
                if (!msk0[r]) u0 = W[woff0[r] + ((T) + 5) * 16];         \
                if (!msk1[r]) u1 = W[woff1[r] + ((T) + 5) * 16];         \
                wv0[(T + 1) & 3][r] = u0;                                \
                wv1[(T + 1) & 3][r] = u1;                                \
            }                                                            \
        }                                                                \
        if (!(LAST)) {                                                   \
            STAGE((T) + 2, ((T) + 2) & 3);                               \
            STAGE((T) + 3, ((T) + 3) & 3);                               \
        }                                                                \
        __builtin_amdgcn_sched_barrier(0);                               \
        TCOMP((T),     wcA0, wcA1);                                      \
        TCOMP((T) + 1, wcB0, wcB1);                                      \
        if (!(LAST)) {                                                   \
            /* 16 stores are the newest VMEM ops; everything older       \
               (W-pref + 4 stage loads) must be retired. */              \
            asm volatile("s_waitcnt vmcnt(16)" ::: "memory");            \
            __builtin_amdgcn_s_barrier();                                \
        }                                                                \
    }

    STAGE(0, 0);
    STAGE(1, 1);
    __syncthreads();   // one-time full drain: tiles 0,1 staged

    PHASE(0,  1, 0);
    PHASE(2,  1, 0);
    PHASE(4,  1, 0);
    PHASE(6,  1, 0);
    PHASE(8,  1, 0);
    PHASE(10, 1, 0);
    PHASE(12, 0, 0);   // no W prefetch (would read past col range)
    PHASE(14, 0, 1);   // last: no stage, no barrier
#undef PHASE
#undef TCOMP
#undef STAGE
}

extern "C" void kernel_launch(void* const* d_in, const int* in_sizes, int n_in,
                              void* d_out, int out_size, void* d_ws, size_t ws_size,
                              hipStream_t stream) {
    (void)in_sizes; (void)n_in; (void)out_size; (void)ws_size;

    const int*   x    = (const int*)d_in[0];
    const int*   mask = (const int*)d_in[1];
    const float* W    = (const float*)d_in[2];
    const float* A    = (const float*)d_in[3];
    const float* B    = (const float*)d_in[4];
    float*       out  = (float*)d_out;

    unsigned short* Abf   = (unsigned short*)d_ws;                       // 2 MiB
    unsigned short* Bfrag = (unsigned short*)((char*)d_ws + (2u << 20)); // 2 MiB

    prep_kernel<<<dim3(1536), dim3(256), 0, stream>>>(A, B, Abf, Bfrag);

    dim3 grid(NTOK / TPB, NCOL / CPB);   // (64, 16) = 1024 blocks
    emb_lora_mfma<<<grid, dim3(256), 0, stream>>>(x, mask, W, Abf, Bfrag, out);
}